// Round 1
// baseline (460.465 us; speedup 1.0000x reference)
//
#include <hip/hip_runtime.h>

// ---------------- problem constants ----------------
#define FIN   256
#define F1    128
#define F2    64

// ---------------- degree count ----------------
__global__ void count_deg(const int* __restrict__ dst, int* __restrict__ deg, int E) {
    int i = blockIdx.x * blockDim.x + threadIdx.x;
    if (i < E) atomicAdd(&deg[dst[i]], 1);
}

// ---------------- single-block scan: rowptr/cursor/dinv ----------------
__global__ __launch_bounds__(1024) void scan_deg(const int* __restrict__ deg,
                                                 int* __restrict__ rowptr,
                                                 int* __restrict__ cursor,
                                                 float* __restrict__ dinv,
                                                 int n, int E) {
    __shared__ int buf[2][1024];
    int t = threadIdx.x;
    int chunk = (n + 1023) / 1024;
    int beg = t * chunk;
    int end = beg + chunk; if (end > n) end = n;
    int s = 0;
    for (int i = beg; i < end; ++i) s += deg[i];
    buf[0][t] = s;
    __syncthreads();
    int cur = 0;
    for (int off = 1; off < 1024; off <<= 1) {
        int v = buf[cur][t];
        if (t >= off) v += buf[cur][t - off];
        buf[cur ^ 1][t] = v;
        cur ^= 1;
        __syncthreads();
    }
    int run = (t == 0) ? 0 : buf[cur][t - 1];
    for (int i = beg; i < end; ++i) {
        int d = deg[i];
        rowptr[i] = run;
        cursor[i] = run;
        dinv[i]   = rsqrtf((float)(d + 1));   // +1 self loop; deg>0 always
        run += d;
    }
    if (t == 0) rowptr[n] = E;
}

// ---------------- CSR fill ----------------
__global__ void fill_csr(const int* __restrict__ src, const int* __restrict__ dst,
                         int* __restrict__ cursor, int* __restrict__ csr, int E) {
    int i = blockIdx.x * blockDim.x + threadIdx.x;
    if (i < E) {
        int d = dst[i];
        int pos = atomicAdd(&cursor[d], 1);
        csr[pos] = src[i];
    }
}

// ---------------- f32 tiled GEMM with dinv-scaled epilogue ----------------
// C[M][BN] = dinv[row] * (A[M][K] @ B[K][BN]);  BM=64, 256 threads, 4xTN per thread
template <int BN, int K>
__global__ __launch_bounds__(256) void gemm_scale(const float* __restrict__ A,
                                                  const float* __restrict__ B,
                                                  const float* __restrict__ dinv,
                                                  float* __restrict__ C, int M) {
    constexpr int BK = 32;
    constexpr int TN = BN / 16;             // 8 (BN=128) or 4 (BN=64)
    __shared__ float As[BK][64 + 4];        // transposed A tile: As[k][row]
    __shared__ float Bs[BK][BN + 4];

    int tid = threadIdx.x;
    int tx = tid & 15;                      // col group
    int ty = tid >> 4;                      // row group (0..15)
    int row0 = blockIdx.x * 64;

    float acc[4][TN];
#pragma unroll
    for (int i = 0; i < 4; ++i)
#pragma unroll
        for (int j = 0; j < TN; ++j) acc[i][j] = 0.f;

    for (int k0 = 0; k0 < K; k0 += BK) {
        // stage A tile (64 x 32): 512 float4s, 2 per thread, store transposed
#pragma unroll
        for (int l = 0; l < 2; ++l) {
            int f = tid + l * 256;
            int r = f >> 3, c4 = f & 7;
            int gr = row0 + r;
            float4 v = make_float4(0.f, 0.f, 0.f, 0.f);
            if (gr < M) v = *(const float4*)&A[(size_t)gr * K + k0 + c4 * 4];
            As[c4 * 4 + 0][r] = v.x;
            As[c4 * 4 + 1][r] = v.y;
            As[c4 * 4 + 2][r] = v.z;
            As[c4 * 4 + 3][r] = v.w;
        }
        // stage B tile (32 x BN): BN/32 float4s per thread
#pragma unroll
        for (int l = 0; l < BN / 32; ++l) {
            int f = tid + l * 256;
            int r = f / (BN / 4), c4 = f % (BN / 4);
            float4 v = *(const float4*)&B[(size_t)(k0 + r) * BN + c4 * 4];
            *(float4*)&Bs[r][c4 * 4] = v;
        }
        __syncthreads();
#pragma unroll
        for (int k = 0; k < BK; ++k) {
            float4 a = *(const float4*)&As[k][ty * 4];
            float av[4] = {a.x, a.y, a.z, a.w};
            float bv[TN];
#pragma unroll
            for (int j4 = 0; j4 < TN / 4; ++j4) {
                float4 b = *(const float4*)&Bs[k][tx * TN + j4 * 4];
                bv[j4 * 4 + 0] = b.x; bv[j4 * 4 + 1] = b.y;
                bv[j4 * 4 + 2] = b.z; bv[j4 * 4 + 3] = b.w;
            }
#pragma unroll
            for (int i = 0; i < 4; ++i)
#pragma unroll
                for (int j = 0; j < TN; ++j)
                    acc[i][j] = fmaf(av[i], bv[j], acc[i][j]);
        }
        __syncthreads();
    }
#pragma unroll
    for (int i = 0; i < 4; ++i) {
        int gr = row0 + ty * 4 + i;
        if (gr < M) {
            float dv = dinv[gr];
#pragma unroll
            for (int j4 = 0; j4 < TN / 4; ++j4) {
                float4 o;
                o.x = dv * acc[i][j4 * 4 + 0];
                o.y = dv * acc[i][j4 * 4 + 1];
                o.z = dv * acc[i][j4 * 4 + 2];
                o.w = dv * acc[i][j4 * 4 + 3];
                *(float4*)&C[(size_t)gr * BN + tx * TN + j4 * 4] = o;
            }
        }
    }
}

// ---------------- gather aggregation: one wave per node ----------------
// out[v] = act( dinv[v] * (Hs[v] + sum_{s in CSR[v]} Hs[s]) + bias )
template <int F, bool RELU>
__global__ __launch_bounds__(256) void aggregate(const float* __restrict__ Hs,
                                                 const int* __restrict__ rowptr,
                                                 const int* __restrict__ csr,
                                                 const float* __restrict__ dinv,
                                                 const float* __restrict__ bias,
                                                 float* __restrict__ out, int n) {
    int wid  = blockIdx.x * (blockDim.x >> 6) + (threadIdx.x >> 6);
    int lane = threadIdx.x & 63;
    if (wid >= n) return;
    constexpr int PER = F / 64;             // 2 (F=128) or 1 (F=64)
    float acc[PER];
#pragma unroll
    for (int p = 0; p < PER; ++p) acc[p] = Hs[(size_t)wid * F + p * 64 + lane];
    int beg = rowptr[wid], end = rowptr[wid + 1];
    for (int e = beg; e < end; ++e) {
        int s = csr[e];
#pragma unroll
        for (int p = 0; p < PER; ++p) acc[p] += Hs[(size_t)s * F + p * 64 + lane];
    }
    float dv = dinv[wid];
#pragma unroll
    for (int p = 0; p < PER; ++p) {
        float o = dv * acc[p] + bias[p * 64 + lane];
        if (RELU) o = fmaxf(o, 0.f);
        out[(size_t)wid * F + p * 64 + lane] = o;
    }
}

// ---------------- launch ----------------
extern "C" void kernel_launch(void* const* d_in, const int* in_sizes, int n_in,
                              void* d_out, int out_size, void* d_ws, size_t ws_size,
                              hipStream_t stream) {
    const float* x  = (const float*)d_in[0];
    const int*   ei = (const int*)d_in[1];
    const float* W1 = (const float*)d_in[2];
    const float* b1 = (const float*)d_in[3];
    const float* W2 = (const float*)d_in[4];
    const float* b2 = (const float*)d_in[5];
    float* out = (float*)d_out;

    const int N = in_sizes[0] / FIN;     // 50000
    const int E = in_sizes[1] / 2;       // 800000
    const int* src = ei;
    const int* dst = ei + E;

    char* w = (char*)d_ws;
    auto alloc = [&](size_t bytes) {
        void* p = (void*)w;
        w += (bytes + 255) & ~(size_t)255;
        return p;
    };
    int*   deg    = (int*)alloc((size_t)N * 4);
    float* dinv   = (float*)alloc((size_t)N * 4);
    int*   rowptr = (int*)alloc((size_t)(N + 1) * 4);
    int*   cursor = (int*)alloc((size_t)N * 4);
    int*   csr    = (int*)alloc((size_t)E * 4);
    float* Hs1    = (float*)alloc((size_t)N * F1 * 4);   // reused as Hs2
    float* X2     = (float*)alloc((size_t)N * F1 * 4);

    hipMemsetAsync(deg, 0, (size_t)N * 4, stream);
    count_deg<<<(E + 255) / 256, 256, 0, stream>>>(dst, deg, E);
    scan_deg<<<1, 1024, 0, stream>>>(deg, rowptr, cursor, dinv, N, E);
    fill_csr<<<(E + 255) / 256, 256, 0, stream>>>(src, dst, cursor, csr, E);

    // layer 1: Hs1 = dinv * (x @ W1); X2 = relu(dinv*(Hs1[v]+sum Hs1[nbr]) + b1)
    gemm_scale<F1, FIN><<<(N + 63) / 64, 256, 0, stream>>>(x, W1, dinv, Hs1, N);
    aggregate<F1, true><<<(N + 3) / 4, 256, 0, stream>>>(Hs1, rowptr, csr, dinv, b1, X2, N);

    // layer 2: Hs2 = dinv * (X2 @ W2); out = dinv*(Hs2[v]+sum Hs2[nbr]) + b2
    gemm_scale<F2, F1><<<(N + 63) / 64, 256, 0, stream>>>(X2, W2, dinv, Hs1, N);
    aggregate<F2, false><<<(N + 3) / 4, 256, 0, stream>>>(Hs1, rowptr, csr, dinv, b2, out, N);
}

// Round 2
// 340.770 us; speedup vs baseline: 1.3512x; 1.3512x over previous
//
#include <hip/hip_runtime.h>

// ---------------- problem constants ----------------
#define FIN   256
#define F1    128
#define F2    64

// ---------------- degree count ----------------
__global__ void count_deg(const int* __restrict__ dst, int* __restrict__ deg, int E) {
    int i = blockIdx.x * blockDim.x + threadIdx.x;
    if (i < E) atomicAdd(&deg[dst[i]], 1);
}

// ---------------- hierarchical scan, stage 1: per-block sums ----------------
// block b covers elements [b*1024, b*1024+1024); 256 threads, int4 loads
__global__ __launch_bounds__(256) void block_sum(const int* __restrict__ deg,
                                                 int* __restrict__ bsum, int n) {
    int t = threadIdx.x;
    int base = blockIdx.x * 1024 + t * 4;
    int s = 0;
    if (base + 3 < n) {
        int4 v = *(const int4*)&deg[base];
        s = v.x + v.y + v.z + v.w;
    } else {
        for (int i = 0; i < 4; ++i)
            if (base + i < n) s += deg[base + i];
    }
    // wave reduce (64 lanes)
#pragma unroll
    for (int off = 32; off > 0; off >>= 1) s += __shfl_down(s, off, 64);
    __shared__ int ws[4];
    if ((t & 63) == 0) ws[t >> 6] = s;
    __syncthreads();
    if (t == 0) bsum[blockIdx.x] = ws[0] + ws[1] + ws[2] + ws[3];
}

// ---------------- stage 2: exclusive scan of block sums (1 tiny block) ----------------
__global__ void scan_bsums(int* __restrict__ bsum, int nb) {
    if (threadIdx.x == 0) {
        int run = 0;
        for (int i = 0; i < nb; ++i) {
            int v = bsum[i];
            bsum[i] = run;
            run += v;
        }
    }
}

// ---------------- stage 3: per-block exclusive scan + emit rowptr/cursor/dinv ----
__global__ __launch_bounds__(256) void scan_final(const int* __restrict__ deg,
                                                  const int* __restrict__ bsum,
                                                  int* __restrict__ rowptr,
                                                  int* __restrict__ cursor,
                                                  float* __restrict__ dinv,
                                                  int n, int E) {
    __shared__ int buf[2][256];
    int t = threadIdx.x;
    int base = blockIdx.x * 1024 + t * 4;
    int d[4] = {0, 0, 0, 0};
    if (base + 3 < n) {
        int4 v = *(const int4*)&deg[base];
        d[0] = v.x; d[1] = v.y; d[2] = v.z; d[3] = v.w;
    } else {
        for (int i = 0; i < 4; ++i)
            if (base + i < n) d[i] = deg[base + i];
    }
    int tsum = d[0] + d[1] + d[2] + d[3];
    buf[0][t] = tsum;
    __syncthreads();
    int cur = 0;
    for (int off = 1; off < 256; off <<= 1) {
        int v = buf[cur][t];
        if (t >= off) v += buf[cur][t - off];
        buf[cur ^ 1][t] = v;
        cur ^= 1;
        __syncthreads();
    }
    int run = bsum[blockIdx.x] + ((t == 0) ? 0 : buf[cur][t - 1]);
#pragma unroll
    for (int i = 0; i < 4; ++i) {
        int idx = base + i;
        if (idx < n) {
            rowptr[idx] = run;
            cursor[idx] = run;
            dinv[idx]   = rsqrtf((float)(d[i] + 1));  // +1 self loop
            run += d[i];
        }
    }
    if (blockIdx.x == 0 && t == 0) rowptr[n] = E;
}

// ---------------- CSR fill ----------------
__global__ void fill_csr(const int* __restrict__ src, const int* __restrict__ dst,
                         int* __restrict__ cursor, int* __restrict__ csr, int E) {
    int i = blockIdx.x * blockDim.x + threadIdx.x;
    if (i < E) {
        int d = dst[i];
        int pos = atomicAdd(&cursor[d], 1);
        csr[pos] = src[i];
    }
}

// ---------------- f32 tiled GEMM with dinv-scaled epilogue ----------------
// C[M][BN] = dinv[row] * (A[M][K] @ B[K][BN]);  BM=64, 256 threads, 4xTN per thread
template <int BN, int K>
__global__ __launch_bounds__(256) void gemm_scale(const float* __restrict__ A,
                                                  const float* __restrict__ B,
                                                  const float* __restrict__ dinv,
                                                  float* __restrict__ C, int M) {
    constexpr int BK = 32;
    constexpr int TN = BN / 16;             // 8 (BN=128) or 4 (BN=64)
    __shared__ float As[BK][64 + 4];        // transposed A tile: As[k][row]
    __shared__ float Bs[BK][BN + 4];

    int tid = threadIdx.x;
    int tx = tid & 15;                      // col group
    int ty = tid >> 4;                      // row group (0..15)
    int row0 = blockIdx.x * 64;

    float acc[4][TN];
#pragma unroll
    for (int i = 0; i < 4; ++i)
#pragma unroll
        for (int j = 0; j < TN; ++j) acc[i][j] = 0.f;

    for (int k0 = 0; k0 < K; k0 += BK) {
        // stage A tile (64 x 32): 512 float4s, 2 per thread, store transposed
#pragma unroll
        for (int l = 0; l < 2; ++l) {
            int f = tid + l * 256;
            int r = f >> 3, c4 = f & 7;
            int gr = row0 + r;
            float4 v = make_float4(0.f, 0.f, 0.f, 0.f);
            if (gr < M) v = *(const float4*)&A[(size_t)gr * K + k0 + c4 * 4];
            As[c4 * 4 + 0][r] = v.x;
            As[c4 * 4 + 1][r] = v.y;
            As[c4 * 4 + 2][r] = v.z;
            As[c4 * 4 + 3][r] = v.w;
        }
        // stage B tile (32 x BN): BN/32 float4s per thread
#pragma unroll
        for (int l = 0; l < BN / 32; ++l) {
            int f = tid + l * 256;
            int r = f / (BN / 4), c4 = f % (BN / 4);
            float4 v = *(const float4*)&B[(size_t)(k0 + r) * BN + c4 * 4];
            *(float4*)&Bs[r][c4 * 4] = v;
        }
        __syncthreads();
#pragma unroll
        for (int k = 0; k < BK; ++k) {
            float4 a = *(const float4*)&As[k][ty * 4];
            float av[4] = {a.x, a.y, a.z, a.w};
            float bv[TN];
#pragma unroll
            for (int j4 = 0; j4 < TN / 4; ++j4) {
                float4 b = *(const float4*)&Bs[k][tx * TN + j4 * 4];
                bv[j4 * 4 + 0] = b.x; bv[j4 * 4 + 1] = b.y;
                bv[j4 * 4 + 2] = b.z; bv[j4 * 4 + 3] = b.w;
            }
#pragma unroll
            for (int i = 0; i < 4; ++i)
#pragma unroll
                for (int j = 0; j < TN; ++j)
                    acc[i][j] = fmaf(av[i], bv[j], acc[i][j]);
        }
        __syncthreads();
    }
#pragma unroll
    for (int i = 0; i < 4; ++i) {
        int gr = row0 + ty * 4 + i;
        if (gr < M) {
            float dv = dinv[gr];
#pragma unroll
            for (int j4 = 0; j4 < TN / 4; ++j4) {
                float4 o;
                o.x = dv * acc[i][j4 * 4 + 0];
                o.y = dv * acc[i][j4 * 4 + 1];
                o.z = dv * acc[i][j4 * 4 + 2];
                o.w = dv * acc[i][j4 * 4 + 3];
                *(float4*)&C[(size_t)gr * BN + tx * TN + j4 * 4] = o;
            }
        }
    }
}

// ---------------- gather aggregation: one wave per node ----------------
// out[v] = act( dinv[v] * (Hs[v] + sum_{s in CSR[v]} Hs[s]) + bias )
template <int F, bool RELU>
__global__ __launch_bounds__(256) void aggregate(const float* __restrict__ Hs,
                                                 const int* __restrict__ rowptr,
                                                 const int* __restrict__ csr,
                                                 const float* __restrict__ dinv,
                                                 const float* __restrict__ bias,
                                                 float* __restrict__ out, int n) {
    int wid  = blockIdx.x * (blockDim.x >> 6) + (threadIdx.x >> 6);
    int lane = threadIdx.x & 63;
    if (wid >= n) return;
    constexpr int PER = F / 64;             // 2 (F=128) or 1 (F=64)
    float acc[PER];
#pragma unroll
    for (int p = 0; p < PER; ++p) acc[p] = Hs[(size_t)wid * F + p * 64 + lane];
    int beg = rowptr[wid], end = rowptr[wid + 1];
    for (int e = beg; e < end; ++e) {
        int s = csr[e];
#pragma unroll
        for (int p = 0; p < PER; ++p) acc[p] += Hs[(size_t)s * F + p * 64 + lane];
    }
    float dv = dinv[wid];
#pragma unroll
    for (int p = 0; p < PER; ++p) {
        float o = dv * acc[p] + bias[p * 64 + lane];
        if (RELU) o = fmaxf(o, 0.f);
        out[(size_t)wid * F + p * 64 + lane] = o;
    }
}

// ---------------- launch ----------------
extern "C" void kernel_launch(void* const* d_in, const int* in_sizes, int n_in,
                              void* d_out, int out_size, void* d_ws, size_t ws_size,
                              hipStream_t stream) {
    const float* x  = (const float*)d_in[0];
    const int*   ei = (const int*)d_in[1];
    const float* W1 = (const float*)d_in[2];
    const float* b1 = (const float*)d_in[3];
    const float* W2 = (const float*)d_in[4];
    const float* b2 = (const float*)d_in[5];
    float* out = (float*)d_out;

    const int N = in_sizes[0] / FIN;     // 50000
    const int E = in_sizes[1] / 2;       // 800000
    const int* src = ei;
    const int* dst = ei + E;

    char* w = (char*)d_ws;
    auto alloc = [&](size_t bytes) {
        void* p = (void*)w;
        w += (bytes + 255) & ~(size_t)255;
        return p;
    };
    int*   deg    = (int*)alloc((size_t)N * 4);
    float* dinv   = (float*)alloc((size_t)N * 4);
    int*   rowptr = (int*)alloc((size_t)(N + 1) * 4);
    int*   cursor = (int*)alloc((size_t)N * 4);
    int*   csr    = (int*)alloc((size_t)E * 4);
    int*   bsum   = (int*)alloc((size_t)256 * 4);
    float* Hs1    = (float*)alloc((size_t)N * F1 * 4);   // reused as Hs2
    float* X2     = (float*)alloc((size_t)N * F1 * 4);

    const int nb = (N + 1023) / 1024;    // scan blocks (49)

    hipMemsetAsync(deg, 0, (size_t)N * 4, stream);
    count_deg<<<(E + 255) / 256, 256, 0, stream>>>(dst, deg, E);
    block_sum<<<nb, 256, 0, stream>>>(deg, bsum, N);
    scan_bsums<<<1, 64, 0, stream>>>(bsum, nb);
    scan_final<<<nb, 256, 0, stream>>>(deg, bsum, rowptr, cursor, dinv, N, E);
    fill_csr<<<(E + 255) / 256, 256, 0, stream>>>(src, dst, cursor, csr, E);

    // layer 1: Hs1 = dinv * (x @ W1); X2 = relu(dinv*(Hs1[v]+sum Hs1[nbr]) + b1)
    gemm_scale<F1, FIN><<<(N + 63) / 64, 256, 0, stream>>>(x, W1, dinv, Hs1, N);
    aggregate<F1, true><<<(N + 3) / 4, 256, 0, stream>>>(Hs1, rowptr, csr, dinv, b1, X2, N);

    // layer 2: Hs2 = dinv * (X2 @ W2); out = dinv*(Hs2[v]+sum Hs2[nbr]) + b2
    gemm_scale<F2, F1><<<(N + 63) / 64, 256, 0, stream>>>(X2, W2, dinv, Hs1, N);
    aggregate<F2, false><<<(N + 3) / 4, 256, 0, stream>>>(Hs1, rowptr, csr, dinv, b2, out, N);
}

// Round 3
// 269.579 us; speedup vs baseline: 1.7081x; 1.2641x over previous
//
#include <hip/hip_runtime.h>

// ---------------- problem constants ----------------
#define FIN   256
#define F1    128
#define F2    64

// ---------------- degree count ----------------
__global__ void count_deg(const int* __restrict__ dst, int* __restrict__ deg, int E) {
    int i = blockIdx.x * blockDim.x + threadIdx.x;
    if (i < E) atomicAdd(&deg[dst[i]], 1);
}

// ---------------- hierarchical scan, stage 1: per-block sums ----------------
__global__ __launch_bounds__(256) void block_sum(const int* __restrict__ deg,
                                                 int* __restrict__ bsum, int n) {
    int t = threadIdx.x;
    int base = blockIdx.x * 1024 + t * 4;
    int s = 0;
    if (base + 3 < n) {
        int4 v = *(const int4*)&deg[base];
        s = v.x + v.y + v.z + v.w;
    } else {
        for (int i = 0; i < 4; ++i)
            if (base + i < n) s += deg[base + i];
    }
#pragma unroll
    for (int off = 32; off > 0; off >>= 1) s += __shfl_down(s, off, 64);
    __shared__ int ws[4];
    if ((t & 63) == 0) ws[t >> 6] = s;
    __syncthreads();
    if (t == 0) bsum[blockIdx.x] = ws[0] + ws[1] + ws[2] + ws[3];
}

// ---------------- stage 2: exclusive scan of block sums ----------------
__global__ void scan_bsums(int* __restrict__ bsum, int nb) {
    if (threadIdx.x == 0) {
        int run = 0;
        for (int i = 0; i < nb; ++i) {
            int v = bsum[i];
            bsum[i] = run;
            run += v;
        }
    }
}

// ---------------- stage 3: per-block exclusive scan + emit rowptr/cursor/dinv ----
__global__ __launch_bounds__(256) void scan_final(const int* __restrict__ deg,
                                                  const int* __restrict__ bsum,
                                                  int* __restrict__ rowptr,
                                                  int* __restrict__ cursor,
                                                  float* __restrict__ dinv,
                                                  int n, int E) {
    __shared__ int buf[2][256];
    int t = threadIdx.x;
    int base = blockIdx.x * 1024 + t * 4;
    int d[4] = {0, 0, 0, 0};
    if (base + 3 < n) {
        int4 v = *(const int4*)&deg[base];
        d[0] = v.x; d[1] = v.y; d[2] = v.z; d[3] = v.w;
    } else {
        for (int i = 0; i < 4; ++i)
            if (base + i < n) d[i] = deg[base + i];
    }
    int tsum = d[0] + d[1] + d[2] + d[3];
    buf[0][t] = tsum;
    __syncthreads();
    int cur = 0;
    for (int off = 1; off < 256; off <<= 1) {
        int v = buf[cur][t];
        if (t >= off) v += buf[cur][t - off];
        buf[cur ^ 1][t] = v;
        cur ^= 1;
        __syncthreads();
    }
    int run = bsum[blockIdx.x] + ((t == 0) ? 0 : buf[cur][t - 1]);
#pragma unroll
    for (int i = 0; i < 4; ++i) {
        int idx = base + i;
        if (idx < n) {
            rowptr[idx] = run;
            cursor[idx] = run;
            dinv[idx]   = rsqrtf((float)(d[i] + 1));  // +1 self loop
            run += d[i];
        }
    }
    if (blockIdx.x == 0 && t == 0) rowptr[n] = E;
}

// ---------------- CSR fill ----------------
__global__ void fill_csr(const int* __restrict__ src, const int* __restrict__ dst,
                         int* __restrict__ cursor, int* __restrict__ csr, int E) {
    int i = blockIdx.x * blockDim.x + threadIdx.x;
    if (i < E) {
        int d = dst[i];
        int pos = atomicAdd(&cursor[d], 1);
        csr[pos] = src[i];
    }
}

// ---------------- f32 tiled GEMM with dinv-scaled epilogue ----------------
template <int BN, int K>
__global__ __launch_bounds__(256) void gemm_scale(const float* __restrict__ A,
                                                  const float* __restrict__ B,
                                                  const float* __restrict__ dinv,
                                                  float* __restrict__ C, int M) {
    constexpr int BK = 32;
    constexpr int TN = BN / 16;
    __shared__ float As[BK][64 + 4];
    __shared__ float Bs[BK][BN + 4];

    int tid = threadIdx.x;
    int tx = tid & 15;
    int ty = tid >> 4;
    int row0 = blockIdx.x * 64;

    float acc[4][TN];
#pragma unroll
    for (int i = 0; i < 4; ++i)
#pragma unroll
        for (int j = 0; j < TN; ++j) acc[i][j] = 0.f;

    for (int k0 = 0; k0 < K; k0 += BK) {
#pragma unroll
        for (int l = 0; l < 2; ++l) {
            int f = tid + l * 256;
            int r = f >> 3, c4 = f & 7;
            int gr = row0 + r;
            float4 v = make_float4(0.f, 0.f, 0.f, 0.f);
            if (gr < M) v = *(const float4*)&A[(size_t)gr * K + k0 + c4 * 4];
            As[c4 * 4 + 0][r] = v.x;
            As[c4 * 4 + 1][r] = v.y;
            As[c4 * 4 + 2][r] = v.z;
            As[c4 * 4 + 3][r] = v.w;
        }
#pragma unroll
        for (int l = 0; l < BN / 32; ++l) {
            int f = tid + l * 256;
            int r = f / (BN / 4), c4 = f % (BN / 4);
            float4 v = *(const float4*)&B[(size_t)(k0 + r) * BN + c4 * 4];
            *(float4*)&Bs[r][c4 * 4] = v;
        }
        __syncthreads();
#pragma unroll
        for (int k = 0; k < BK; ++k) {
            float4 a = *(const float4*)&As[k][ty * 4];
            float av[4] = {a.x, a.y, a.z, a.w};
            float bv[TN];
#pragma unroll
            for (int j4 = 0; j4 < TN / 4; ++j4) {
                float4 b = *(const float4*)&Bs[k][tx * TN + j4 * 4];
                bv[j4 * 4 + 0] = b.x; bv[j4 * 4 + 1] = b.y;
                bv[j4 * 4 + 2] = b.z; bv[j4 * 4 + 3] = b.w;
            }
#pragma unroll
            for (int i = 0; i < 4; ++i)
#pragma unroll
                for (int j = 0; j < TN; ++j)
                    acc[i][j] = fmaf(av[i], bv[j], acc[i][j]);
        }
        __syncthreads();
    }
#pragma unroll
    for (int i = 0; i < 4; ++i) {
        int gr = row0 + ty * 4 + i;
        if (gr < M) {
            float dv = dinv[gr];
#pragma unroll
            for (int j4 = 0; j4 < TN / 4; ++j4) {
                float4 o;
                o.x = dv * acc[i][j4 * 4 + 0];
                o.y = dv * acc[i][j4 * 4 + 1];
                o.z = dv * acc[i][j4 * 4 + 2];
                o.w = dv * acc[i][j4 * 4 + 3];
                *(float4*)&C[(size_t)gr * BN + tx * TN + j4 * 4] = o;
            }
        }
    }
}

// ---------------- gather aggregation with deep MLP ----------------
// LPG = F/2 lanes per node; each lane owns features {2*sub, 2*sub+1} (float2).
// out[v] = act( dinv[v] * (Hs[v] + sum_{s in CSR[v]} Hs[s]) + bias )
template <int F, bool RELU>
__global__ __launch_bounds__(256) void aggregate(const float* __restrict__ Hs,
                                                 const int* __restrict__ rowptr,
                                                 const int* __restrict__ csr,
                                                 const float* __restrict__ dinv,
                                                 const float* __restrict__ bias,
                                                 float* __restrict__ out, int n) {
    constexpr int LPG = F / 2;                  // 64 (F=128) or 32 (F=64)
    int gid = (blockIdx.x * blockDim.x + threadIdx.x) / LPG;
    int sub = threadIdx.x & (LPG - 1);
    if (gid >= n) return;
    const int col = sub * 2;

    float2 acc = *(const float2*)&Hs[(size_t)gid * F + col];
    int beg = rowptr[gid], end = rowptr[gid + 1];
    int e = beg;

    // 8-way unrolled main loop: 8 independent row gathers in flight
    for (; e + 8 <= end; e += 8) {
        int s0 = csr[e + 0], s1 = csr[e + 1], s2 = csr[e + 2], s3 = csr[e + 3];
        int s4 = csr[e + 4], s5 = csr[e + 5], s6 = csr[e + 6], s7 = csr[e + 7];
        float2 v0 = *(const float2*)&Hs[(size_t)s0 * F + col];
        float2 v1 = *(const float2*)&Hs[(size_t)s1 * F + col];
        float2 v2 = *(const float2*)&Hs[(size_t)s2 * F + col];
        float2 v3 = *(const float2*)&Hs[(size_t)s3 * F + col];
        float2 v4 = *(const float2*)&Hs[(size_t)s4 * F + col];
        float2 v5 = *(const float2*)&Hs[(size_t)s5 * F + col];
        float2 v6 = *(const float2*)&Hs[(size_t)s6 * F + col];
        float2 v7 = *(const float2*)&Hs[(size_t)s7 * F + col];
        acc.x += ((v0.x + v1.x) + (v2.x + v3.x)) + ((v4.x + v5.x) + (v6.x + v7.x));
        acc.y += ((v0.y + v1.y) + (v2.y + v3.y)) + ((v4.y + v5.y) + (v6.y + v7.y));
    }
    // 4-way
    for (; e + 4 <= end; e += 4) {
        int s0 = csr[e + 0], s1 = csr[e + 1], s2 = csr[e + 2], s3 = csr[e + 3];
        float2 v0 = *(const float2*)&Hs[(size_t)s0 * F + col];
        float2 v1 = *(const float2*)&Hs[(size_t)s1 * F + col];
        float2 v2 = *(const float2*)&Hs[(size_t)s2 * F + col];
        float2 v3 = *(const float2*)&Hs[(size_t)s3 * F + col];
        acc.x += (v0.x + v1.x) + (v2.x + v3.x);
        acc.y += (v0.y + v1.y) + (v2.y + v3.y);
    }
    // scalar tail
    for (; e < end; ++e) {
        int s = csr[e];
        float2 v = *(const float2*)&Hs[(size_t)s * F + col];
        acc.x += v.x;
        acc.y += v.y;
    }

    float dv = dinv[gid];
    float2 o;
    o.x = dv * acc.x + bias[col];
    o.y = dv * acc.y + bias[col + 1];
    if (RELU) { o.x = fmaxf(o.x, 0.f); o.y = fmaxf(o.y, 0.f); }
    *(float2*)&out[(size_t)gid * F + col] = o;
}

// ---------------- launch ----------------
extern "C" void kernel_launch(void* const* d_in, const int* in_sizes, int n_in,
                              void* d_out, int out_size, void* d_ws, size_t ws_size,
                              hipStream_t stream) {
    const float* x  = (const float*)d_in[0];
    const int*   ei = (const int*)d_in[1];
    const float* W1 = (const float*)d_in[2];
    const float* b1 = (const float*)d_in[3];
    const float* W2 = (const float*)d_in[4];
    const float* b2 = (const float*)d_in[5];
    float* out = (float*)d_out;

    const int N = in_sizes[0] / FIN;     // 50000
    const int E = in_sizes[1] / 2;       // 800000
    const int* src = ei;
    const int* dst = ei + E;

    char* w = (char*)d_ws;
    auto alloc = [&](size_t bytes) {
        void* p = (void*)w;
        w += (bytes + 255) & ~(size_t)255;
        return p;
    };
    int*   deg    = (int*)alloc((size_t)N * 4);
    float* dinv   = (float*)alloc((size_t)N * 4);
    int*   rowptr = (int*)alloc((size_t)(N + 1) * 4);
    int*   cursor = (int*)alloc((size_t)N * 4);
    int*   csr    = (int*)alloc((size_t)E * 4);
    int*   bsum   = (int*)alloc((size_t)256 * 4);
    float* Hs1    = (float*)alloc((size_t)N * F1 * 4);   // reused as Hs2
    float* X2     = (float*)alloc((size_t)N * F1 * 4);

    const int nb = (N + 1023) / 1024;

    hipMemsetAsync(deg, 0, (size_t)N * 4, stream);
    count_deg<<<(E + 255) / 256, 256, 0, stream>>>(dst, deg, E);
    block_sum<<<nb, 256, 0, stream>>>(deg, bsum, N);
    scan_bsums<<<1, 64, 0, stream>>>(bsum, nb);
    scan_final<<<nb, 256, 0, stream>>>(deg, bsum, rowptr, cursor, dinv, N, E);
    fill_csr<<<(E + 255) / 256, 256, 0, stream>>>(src, dst, cursor, csr, E);

    // layer 1: Hs1 = dinv * (x @ W1); X2 = relu(dinv*(Hs1[v]+sum Hs1[nbr]) + b1)
    gemm_scale<F1, FIN><<<(N + 63) / 64, 256, 0, stream>>>(x, W1, dinv, Hs1, N);
    {
        int lpg = F1 / 2;                                 // 64 lanes/node
        int blocks = (int)(((size_t)N * lpg + 255) / 256);
        aggregate<F1, true><<<blocks, 256, 0, stream>>>(Hs1, rowptr, csr, dinv, b1, X2, N);
    }

    // layer 2: Hs2 = dinv * (X2 @ W2); out = dinv*(Hs2[v]+sum Hs2[nbr]) + b2
    gemm_scale<F2, F1><<<(N + 63) / 64, 256, 0, stream>>>(X2, W2, dinv, Hs1, N);
    {
        int lpg = F2 / 2;                                 // 32 lanes/node
        int blocks = (int)(((size_t)N * lpg + 255) / 256);
        aggregate<F2, false><<<blocks, 256, 0, stream>>>(Hs1, rowptr, csr, dinv, b2, out, N);
    }
}

// Round 4
// 251.684 us; speedup vs baseline: 1.8295x; 1.0711x over previous
//
#include <hip/hip_runtime.h>

// ---------------- problem constants ----------------
#define FIN   256
#define F1    128
#define F2    64

typedef _Float16 f16x8 __attribute__((ext_vector_type(8)));
typedef _Float16 f16x4 __attribute__((ext_vector_type(4)));
typedef float    f32x4 __attribute__((ext_vector_type(4)));

// ---------------- degree count ----------------
__global__ void count_deg(const int* __restrict__ dst, int* __restrict__ deg, int E) {
    int i = blockIdx.x * blockDim.x + threadIdx.x;
    if (i < E) atomicAdd(&deg[dst[i]], 1);
}

// ---------------- hierarchical scan, stage 1: per-block sums ----------------
__global__ __launch_bounds__(256) void block_sum(const int* __restrict__ deg,
                                                 int* __restrict__ bsum, int n) {
    int t = threadIdx.x;
    int base = blockIdx.x * 1024 + t * 4;
    int s = 0;
    if (base + 3 < n) {
        int4 v = *(const int4*)&deg[base];
        s = v.x + v.y + v.z + v.w;
    } else {
        for (int i = 0; i < 4; ++i)
            if (base + i < n) s += deg[base + i];
    }
#pragma unroll
    for (int off = 32; off > 0; off >>= 1) s += __shfl_down(s, off, 64);
    __shared__ int ws[4];
    if ((t & 63) == 0) ws[t >> 6] = s;
    __syncthreads();
    if (t == 0) bsum[blockIdx.x] = ws[0] + ws[1] + ws[2] + ws[3];
}

// ---------------- stage 2: exclusive scan of block sums ----------------
__global__ void scan_bsums(int* __restrict__ bsum, int nb) {
    if (threadIdx.x == 0) {
        int run = 0;
        for (int i = 0; i < nb; ++i) {
            int v = bsum[i];
            bsum[i] = run;
            run += v;
        }
    }
}

// ---------------- stage 3: per-block exclusive scan + emit rowptr/cursor/dinv ----
__global__ __launch_bounds__(256) void scan_final(const int* __restrict__ deg,
                                                  const int* __restrict__ bsum,
                                                  int* __restrict__ rowptr,
                                                  int* __restrict__ cursor,
                                                  float* __restrict__ dinv,
                                                  int n, int E) {
    __shared__ int buf[2][256];
    int t = threadIdx.x;
    int base = blockIdx.x * 1024 + t * 4;
    int d[4] = {0, 0, 0, 0};
    if (base + 3 < n) {
        int4 v = *(const int4*)&deg[base];
        d[0] = v.x; d[1] = v.y; d[2] = v.z; d[3] = v.w;
    } else {
        for (int i = 0; i < 4; ++i)
            if (base + i < n) d[i] = deg[base + i];
    }
    int tsum = d[0] + d[1] + d[2] + d[3];
    buf[0][t] = tsum;
    __syncthreads();
    int cur = 0;
    for (int off = 1; off < 256; off <<= 1) {
        int v = buf[cur][t];
        if (t >= off) v += buf[cur][t - off];
        buf[cur ^ 1][t] = v;
        cur ^= 1;
        __syncthreads();
    }
    int run = bsum[blockIdx.x] + ((t == 0) ? 0 : buf[cur][t - 1]);
#pragma unroll
    for (int i = 0; i < 4; ++i) {
        int idx = base + i;
        if (idx < n) {
            rowptr[idx] = run;
            cursor[idx] = run;
            dinv[idx]   = rsqrtf((float)(d[i] + 1));  // +1 self loop
            run += d[i];
        }
    }
    if (blockIdx.x == 0 && t == 0) rowptr[n] = E;
}

// ---------------- CSR fill ----------------
__global__ void fill_csr(const int* __restrict__ src, const int* __restrict__ dst,
                         int* __restrict__ cursor, int* __restrict__ csr, int E) {
    int i = blockIdx.x * blockDim.x + threadIdx.x;
    if (i < E) {
        int d = dst[i];
        int pos = atomicAdd(&cursor[d], 1);
        csr[pos] = src[i];
    }
}

// ---------------- W -> W^T f16 conversion ----------------
// W: [K][Nn] f32 row-major -> WT: [Nn][K] f16
__global__ void cvt_wt(const float* __restrict__ W, _Float16* __restrict__ WT,
                       int K, int Nn) {
    int idx = blockIdx.x * blockDim.x + threadIdx.x;
    if (idx < K * Nn) {
        int k = idx / Nn, n = idx % Nn;
        WT[(size_t)n * K + k] = (_Float16)W[idx];
    }
}

// ---------------- f16 MFMA GEMM with dinv-scaled epilogue ----------------
// C[M][BN] = dinv[row] * (A[M][K]_f32 @ W[K][BN]); WT is W^T in f16 [BN][K].
// Block: 256 thr = 4 waves; BM=64 (wave w owns rows w*16..w*16+15); BK=64.
template <int BN, int K>
__global__ __launch_bounds__(256) void gemm_mfma(const float* __restrict__ A,
                                                 const _Float16* __restrict__ WT,
                                                 const float* __restrict__ dinv,
                                                 float* __restrict__ C, int M) {
    constexpr int NB = BN / 16;
    __shared__ _Float16 As[64][72];          // 72: 144B row stride, 16B-aligned

    int tid  = threadIdx.x;
    int wave = tid >> 6, lane = tid & 63;
    int col  = lane & 15, kg = lane >> 4;    // fragment col / k-group
    int row0 = blockIdx.x * 64;

    f32x4 acc[NB];
#pragma unroll
    for (int j = 0; j < NB; ++j) acc[j] = (f32x4){0.f, 0.f, 0.f, 0.f};

    for (int k0 = 0; k0 < K; k0 += 64) {
        // stage A tile 64x64 f32 -> f16 LDS (4 float4 per thread)
#pragma unroll
        for (int l = 0; l < 4; ++l) {
            int f  = l * 256 + tid;          // 0..1023
            int r  = f >> 4;                 // 16 float4 per 64-float row
            int c4 = f & 15;
            int gr = row0 + r;
            float4 v = make_float4(0.f, 0.f, 0.f, 0.f);
            if (gr < M) v = *(const float4*)&A[(size_t)gr * K + k0 + c4 * 4];
            f16x4 h;
            h[0] = (_Float16)v.x; h[1] = (_Float16)v.y;
            h[2] = (_Float16)v.z; h[3] = (_Float16)v.w;
            *(f16x4*)&As[r][c4 * 4] = h;
        }
        __syncthreads();
#pragma unroll
        for (int kk = 0; kk < 2; ++kk) {
            f16x8 a = *(const f16x8*)&As[wave * 16 + col][kk * 32 + kg * 8];
#pragma unroll
            for (int j = 0; j < NB; ++j) {
                f16x8 b = *(const f16x8*)&WT[(size_t)(j * 16 + col) * K + k0 + kk * 32 + kg * 8];
                acc[j] = __builtin_amdgcn_mfma_f32_16x16x32_f16(a, b, acc[j], 0, 0, 0);
            }
        }
        __syncthreads();
    }
    // epilogue: D row = wave*16 + kg*4 + r, col = j*16 + col
    int rbase = row0 + wave * 16 + kg * 4;
#pragma unroll
    for (int r = 0; r < 4; ++r) {
        int m = rbase + r;
        if (m < M) {
            float dv = dinv[m];
#pragma unroll
            for (int j = 0; j < NB; ++j)
                C[(size_t)m * BN + j * 16 + col] = dv * acc[j][r];
        }
    }
}

// ---------------- gather aggregation with deep MLP ----------------
template <int F, bool RELU>
__global__ __launch_bounds__(256) void aggregate(const float* __restrict__ Hs,
                                                 const int* __restrict__ rowptr,
                                                 const int* __restrict__ csr,
                                                 const float* __restrict__ dinv,
                                                 const float* __restrict__ bias,
                                                 float* __restrict__ out, int n) {
    constexpr int LPG = F / 2;                  // 64 (F=128) or 32 (F=64)
    int gid = (blockIdx.x * blockDim.x + threadIdx.x) / LPG;
    int sub = threadIdx.x & (LPG - 1);
    if (gid >= n) return;
    const int col = sub * 2;

    float2 acc = *(const float2*)&Hs[(size_t)gid * F + col];
    int beg = rowptr[gid], end = rowptr[gid + 1];
    int e = beg;

    for (; e + 8 <= end; e += 8) {
        int s0 = csr[e + 0], s1 = csr[e + 1], s2 = csr[e + 2], s3 = csr[e + 3];
        int s4 = csr[e + 4], s5 = csr[e + 5], s6 = csr[e + 6], s7 = csr[e + 7];
        float2 v0 = *(const float2*)&Hs[(size_t)s0 * F + col];
        float2 v1 = *(const float2*)&Hs[(size_t)s1 * F + col];
        float2 v2 = *(const float2*)&Hs[(size_t)s2 * F + col];
        float2 v3 = *(const float2*)&Hs[(size_t)s3 * F + col];
        float2 v4 = *(const float2*)&Hs[(size_t)s4 * F + col];
        float2 v5 = *(const float2*)&Hs[(size_t)s5 * F + col];
        float2 v6 = *(const float2*)&Hs[(size_t)s6 * F + col];
        float2 v7 = *(const float2*)&Hs[(size_t)s7 * F + col];
        acc.x += ((v0.x + v1.x) + (v2.x + v3.x)) + ((v4.x + v5.x) + (v6.x + v7.x));
        acc.y += ((v0.y + v1.y) + (v2.y + v3.y)) + ((v4.y + v5.y) + (v6.y + v7.y));
    }
    for (; e + 4 <= end; e += 4) {
        int s0 = csr[e + 0], s1 = csr[e + 1], s2 = csr[e + 2], s3 = csr[e + 3];
        float2 v0 = *(const float2*)&Hs[(size_t)s0 * F + col];
        float2 v1 = *(const float2*)&Hs[(size_t)s1 * F + col];
        float2 v2 = *(const float2*)&Hs[(size_t)s2 * F + col];
        float2 v3 = *(const float2*)&Hs[(size_t)s3 * F + col];
        acc.x += (v0.x + v1.x) + (v2.x + v3.x);
        acc.y += (v0.y + v1.y) + (v2.y + v3.y);
    }
    for (; e < end; ++e) {
        int s = csr[e];
        float2 v = *(const float2*)&Hs[(size_t)s * F + col];
        acc.x += v.x;
        acc.y += v.y;
    }

    float dv = dinv[gid];
    float2 o;
    o.x = dv * acc.x + bias[col];
    o.y = dv * acc.y + bias[col + 1];
    if (RELU) { o.x = fmaxf(o.x, 0.f); o.y = fmaxf(o.y, 0.f); }
    *(float2*)&out[(size_t)gid * F + col] = o;
}

// ---------------- launch ----------------
extern "C" void kernel_launch(void* const* d_in, const int* in_sizes, int n_in,
                              void* d_out, int out_size, void* d_ws, size_t ws_size,
                              hipStream_t stream) {
    const float* x  = (const float*)d_in[0];
    const int*   ei = (const int*)d_in[1];
    const float* W1 = (const float*)d_in[2];
    const float* b1 = (const float*)d_in[3];
    const float* W2 = (const float*)d_in[4];
    const float* b2 = (const float*)d_in[5];
    float* out = (float*)d_out;

    const int N = in_sizes[0] / FIN;     // 50000
    const int E = in_sizes[1] / 2;       // 800000
    const int* src = ei;
    const int* dst = ei + E;

    char* w = (char*)d_ws;
    auto alloc = [&](size_t bytes) {
        void* p = (void*)w;
        w += (bytes + 255) & ~(size_t)255;
        return p;
    };
    int*      deg    = (int*)alloc((size_t)N * 4);
    float*    dinv   = (float*)alloc((size_t)N * 4);
    int*      rowptr = (int*)alloc((size_t)(N + 1) * 4);
    int*      cursor = (int*)alloc((size_t)N * 4);
    int*      csr    = (int*)alloc((size_t)E * 4);
    int*      bsum   = (int*)alloc((size_t)256 * 4);
    _Float16* WT1    = (_Float16*)alloc((size_t)FIN * F1 * 2);
    _Float16* WT2    = (_Float16*)alloc((size_t)F1 * F2 * 2);
    float*    Hs1    = (float*)alloc((size_t)N * F1 * 4);   // reused as Hs2
    float*    X2     = (float*)alloc((size_t)N * F1 * 4);

    const int nb = (N + 1023) / 1024;

    hipMemsetAsync(deg, 0, (size_t)N * 4, stream);
    count_deg<<<(E + 255) / 256, 256, 0, stream>>>(dst, deg, E);
    block_sum<<<nb, 256, 0, stream>>>(deg, bsum, N);
    scan_bsums<<<1, 64, 0, stream>>>(bsum, nb);
    scan_final<<<nb, 256, 0, stream>>>(deg, bsum, rowptr, cursor, dinv, N, E);
    fill_csr<<<(E + 255) / 256, 256, 0, stream>>>(src, dst, cursor, csr, E);
    cvt_wt<<<(FIN * F1 + 255) / 256, 256, 0, stream>>>(W1, WT1, FIN, F1);
    cvt_wt<<<(F1 * F2 + 255) / 256, 256, 0, stream>>>(W2, WT2, F1, F2);

    // layer 1: Hs1 = dinv * (x @ W1); X2 = relu(dinv*(Hs1[v]+sum Hs1[nbr]) + b1)
    gemm_mfma<F1, FIN><<<(N + 63) / 64, 256, 0, stream>>>(x, WT1, dinv, Hs1, N);
    {
        int lpg = F1 / 2;
        int blocks = (int)(((size_t)N * lpg + 255) / 256);
        aggregate<F1, true><<<blocks, 256, 0, stream>>>(Hs1, rowptr, csr, dinv, b1, X2, N);
    }

    // layer 2: Hs2 = dinv * (X2 @ W2); out = dinv*(Hs2[v]+sum Hs2[nbr]) + b2
    gemm_mfma<F2, F1><<<(N + 63) / 64, 256, 0, stream>>>(X2, WT2, dinv, Hs1, N);
    {
        int lpg = F2 / 2;
        int blocks = (int)(((size_t)N * lpg + 255) / 256);
        aggregate<F2, false><<<blocks, 256, 0, stream>>>(Hs1, rowptr, csr, dinv, b2, out, N);
    }
}

// Round 5
// 212.919 us; speedup vs baseline: 2.1626x; 1.1821x over previous
//
#include <hip/hip_runtime.h>

// ---------------- problem constants ----------------
#define FIN   256
#define F1    128
#define F2    64

typedef _Float16 f16x8 __attribute__((ext_vector_type(8)));
typedef _Float16 f16x4 __attribute__((ext_vector_type(4)));
typedef float    f32x4 __attribute__((ext_vector_type(4)));

// ---------------- degree count ----------------
__global__ void count_deg(const int* __restrict__ dst, int* __restrict__ deg, int E) {
    int i = blockIdx.x * blockDim.x + threadIdx.x;
    if (i < E) atomicAdd(&deg[dst[i]], 1);
}

// ---------------- hierarchical scan, stage 1: per-block sums ----------------
__global__ __launch_bounds__(256) void block_sum(const int* __restrict__ deg,
                                                 int* __restrict__ bsum, int n) {
    int t = threadIdx.x;
    int base = blockIdx.x * 1024 + t * 4;
    int s = 0;
    if (base + 3 < n) {
        int4 v = *(const int4*)&deg[base];
        s = v.x + v.y + v.z + v.w;
    } else {
        for (int i = 0; i < 4; ++i)
            if (base + i < n) s += deg[base + i];
    }
#pragma unroll
    for (int off = 32; off > 0; off >>= 1) s += __shfl_down(s, off, 64);
    __shared__ int ws[4];
    if ((t & 63) == 0) ws[t >> 6] = s;
    __syncthreads();
    if (t == 0) bsum[blockIdx.x] = ws[0] + ws[1] + ws[2] + ws[3];
}

// ---------------- stage 2: exclusive scan of block sums ----------------
__global__ void scan_bsums(int* __restrict__ bsum, int nb) {
    if (threadIdx.x == 0) {
        int run = 0;
        for (int i = 0; i < nb; ++i) {
            int v = bsum[i];
            bsum[i] = run;
            run += v;
        }
    }
}

// ---------------- stage 3: per-block exclusive scan + emit rowptr/cursor/dinv ----
__global__ __launch_bounds__(256) void scan_final(const int* __restrict__ deg,
                                                  const int* __restrict__ bsum,
                                                  int* __restrict__ rowptr,
                                                  int* __restrict__ cursor,
                                                  float* __restrict__ dinv,
                                                  int n, int E) {
    __shared__ int buf[2][256];
    int t = threadIdx.x;
    int base = blockIdx.x * 1024 + t * 4;
    int d[4] = {0, 0, 0, 0};
    if (base + 3 < n) {
        int4 v = *(const int4*)&deg[base];
        d[0] = v.x; d[1] = v.y; d[2] = v.z; d[3] = v.w;
    } else {
        for (int i = 0; i < 4; ++i)
            if (base + i < n) d[i] = deg[base + i];
    }
    int tsum = d[0] + d[1] + d[2] + d[3];
    buf[0][t] = tsum;
    __syncthreads();
    int cur = 0;
    for (int off = 1; off < 256; off <<= 1) {
        int v = buf[cur][t];
        if (t >= off) v += buf[cur][t - off];
        buf[cur ^ 1][t] = v;
        cur ^= 1;
        __syncthreads();
    }
    int run = bsum[blockIdx.x] + ((t == 0) ? 0 : buf[cur][t - 1]);
#pragma unroll
    for (int i = 0; i < 4; ++i) {
        int idx = base + i;
        if (idx < n) {
            rowptr[idx] = run;
            cursor[idx] = run;
            dinv[idx]   = rsqrtf((float)(d[i] + 1));  // +1 self loop
            run += d[i];
        }
    }
    if (blockIdx.x == 0 && t == 0) rowptr[n] = E;
}

// ---------------- CSR fill ----------------
__global__ void fill_csr(const int* __restrict__ src, const int* __restrict__ dst,
                         int* __restrict__ cursor, int* __restrict__ csr, int E) {
    int i = blockIdx.x * blockDim.x + threadIdx.x;
    if (i < E) {
        int d = dst[i];
        int pos = atomicAdd(&cursor[d], 1);
        csr[pos] = src[i];
    }
}

// ---------------- W -> W^T f16 conversion ----------------
__global__ void cvt_wt(const float* __restrict__ W, _Float16* __restrict__ WT,
                       int K, int Nn) {
    int idx = blockIdx.x * blockDim.x + threadIdx.x;
    if (idx < K * Nn) {
        int k = idx / Nn, n = idx % Nn;
        WT[(size_t)n * K + k] = (_Float16)W[idx];
    }
}

// ---------------- f16 MFMA GEMM, f16 output, dinv-scaled epilogue ----------------
// Ch[M][BN]_f16 = dinv[row] * (A[M][K]_f32 @ W[K][BN]); WT is W^T f16 [BN][K].
template <int BN, int K>
__global__ __launch_bounds__(256) void gemm_mfma(const float* __restrict__ A,
                                                 const _Float16* __restrict__ WT,
                                                 const float* __restrict__ dinv,
                                                 _Float16* __restrict__ Ch, int M) {
    constexpr int NB = BN / 16;
    __shared__ _Float16 As[64][72];          // 144B row stride, 16B-aligned

    int tid  = threadIdx.x;
    int wave = tid >> 6, lane = tid & 63;
    int col  = lane & 15, kg = lane >> 4;
    int row0 = blockIdx.x * 64;

    f32x4 acc[NB];
#pragma unroll
    for (int j = 0; j < NB; ++j) acc[j] = (f32x4){0.f, 0.f, 0.f, 0.f};

    for (int k0 = 0; k0 < K; k0 += 64) {
#pragma unroll
        for (int l = 0; l < 4; ++l) {
            int f  = l * 256 + tid;
            int r  = f >> 4;
            int c4 = f & 15;
            int gr = row0 + r;
            float4 v = make_float4(0.f, 0.f, 0.f, 0.f);
            if (gr < M) v = *(const float4*)&A[(size_t)gr * K + k0 + c4 * 4];
            f16x4 h;
            h[0] = (_Float16)v.x; h[1] = (_Float16)v.y;
            h[2] = (_Float16)v.z; h[3] = (_Float16)v.w;
            *(f16x4*)&As[r][c4 * 4] = h;
        }
        __syncthreads();
#pragma unroll
        for (int kk = 0; kk < 2; ++kk) {
            f16x8 a = *(const f16x8*)&As[wave * 16 + col][kk * 32 + kg * 8];
#pragma unroll
            for (int j = 0; j < NB; ++j) {
                f16x8 b = *(const f16x8*)&WT[(size_t)(j * 16 + col) * K + k0 + kk * 32 + kg * 8];
                acc[j] = __builtin_amdgcn_mfma_f32_16x16x32_f16(a, b, acc[j], 0, 0, 0);
            }
        }
        __syncthreads();
    }
    int rbase = row0 + wave * 16 + kg * 4;
#pragma unroll
    for (int r = 0; r < 4; ++r) {
        int m = rbase + r;
        if (m < M) {
            float dv = dinv[m];
#pragma unroll
            for (int j = 0; j < NB; ++j)
                Ch[(size_t)m * BN + j * 16 + col] = (_Float16)(dv * acc[j][r]);
        }
    }
}

// ---------------- gather aggregation: f16 rows, f32 accumulate ----------------
// LPG = F/4 lanes per node; lane owns features col..col+3 (f16x4, 8B load).
// out[v] = act( dinv[v] * (Hs[v] + sum_{s in CSR[v]} Hs[s]) + bias )
template <int F, bool RELU>
__global__ __launch_bounds__(256) void aggregate(const _Float16* __restrict__ Hs,
                                                 const int* __restrict__ rowptr,
                                                 const int* __restrict__ csr,
                                                 const float* __restrict__ dinv,
                                                 const float* __restrict__ bias,
                                                 float* __restrict__ out, int n) {
    constexpr int LPG = F / 4;                  // 32 (F=128) or 16 (F=64)
    int gid = (blockIdx.x * blockDim.x + threadIdx.x) / LPG;
    int sub = threadIdx.x & (LPG - 1);
    if (gid >= n) return;
    const int col = sub * 4;

    f16x4 h = *(const f16x4*)&Hs[(size_t)gid * F + col];
    float a0 = (float)h[0], a1 = (float)h[1], a2 = (float)h[2], a3 = (float)h[3];

    int beg = rowptr[gid], end = rowptr[gid + 1];
    int e = beg;

    for (; e + 8 <= end; e += 8) {
        int s0 = csr[e + 0], s1 = csr[e + 1], s2 = csr[e + 2], s3 = csr[e + 3];
        int s4 = csr[e + 4], s5 = csr[e + 5], s6 = csr[e + 6], s7 = csr[e + 7];
        f16x4 v0 = *(const f16x4*)&Hs[(size_t)s0 * F + col];
        f16x4 v1 = *(const f16x4*)&Hs[(size_t)s1 * F + col];
        f16x4 v2 = *(const f16x4*)&Hs[(size_t)s2 * F + col];
        f16x4 v3 = *(const f16x4*)&Hs[(size_t)s3 * F + col];
        f16x4 v4 = *(const f16x4*)&Hs[(size_t)s4 * F + col];
        f16x4 v5 = *(const f16x4*)&Hs[(size_t)s5 * F + col];
        f16x4 v6 = *(const f16x4*)&Hs[(size_t)s6 * F + col];
        f16x4 v7 = *(const f16x4*)&Hs[(size_t)s7 * F + col];
        a0 += (((float)v0[0] + (float)v1[0]) + ((float)v2[0] + (float)v3[0]))
            + (((float)v4[0] + (float)v5[0]) + ((float)v6[0] + (float)v7[0]));
        a1 += (((float)v0[1] + (float)v1[1]) + ((float)v2[1] + (float)v3[1]))
            + (((float)v4[1] + (float)v5[1]) + ((float)v6[1] + (float)v7[1]));
        a2 += (((float)v0[2] + (float)v1[2]) + ((float)v2[2] + (float)v3[2]))
            + (((float)v4[2] + (float)v5[2]) + ((float)v6[2] + (float)v7[2]));
        a3 += (((float)v0[3] + (float)v1[3]) + ((float)v2[3] + (float)v3[3]))
            + (((float)v4[3] + (float)v5[3]) + ((float)v6[3] + (float)v7[3]));
    }
    for (; e + 4 <= end; e += 4) {
        int s0 = csr[e + 0], s1 = csr[e + 1], s2 = csr[e + 2], s3 = csr[e + 3];
        f16x4 v0 = *(const f16x4*)&Hs[(size_t)s0 * F + col];
        f16x4 v1 = *(const f16x4*)&Hs[(size_t)s1 * F + col];
        f16x4 v2 = *(const f16x4*)&Hs[(size_t)s2 * F + col];
        f16x4 v3 = *(const f16x4*)&Hs[(size_t)s3 * F + col];
        a0 += ((float)v0[0] + (float)v1[0]) + ((float)v2[0] + (float)v3[0]);
        a1 += ((float)v0[1] + (float)v1[1]) + ((float)v2[1] + (float)v3[1]);
        a2 += ((float)v0[2] + (float)v1[2]) + ((float)v2[2] + (float)v3[2]);
        a3 += ((float)v0[3] + (float)v1[3]) + ((float)v2[3] + (float)v3[3]);
    }
    for (; e < end; ++e) {
        int s = csr[e];
        f16x4 v = *(const f16x4*)&Hs[(size_t)s * F + col];
        a0 += (float)v[0]; a1 += (float)v[1]; a2 += (float)v[2]; a3 += (float)v[3];
    }

    float dv = dinv[gid];
    float4 bb = *(const float4*)&bias[col];
    float4 o;
    o.x = dv * a0 + bb.x;
    o.y = dv * a1 + bb.y;
    o.z = dv * a2 + bb.z;
    o.w = dv * a3 + bb.w;
    if (RELU) {
        o.x = fmaxf(o.x, 0.f); o.y = fmaxf(o.y, 0.f);
        o.z = fmaxf(o.z, 0.f); o.w = fmaxf(o.w, 0.f);
    }
    *(float4*)&out[(size_t)gid * F + col] = o;
}

// ---------------- launch ----------------
extern "C" void kernel_launch(void* const* d_in, const int* in_sizes, int n_in,
                              void* d_out, int out_size, void* d_ws, size_t ws_size,
                              hipStream_t stream) {
    const float* x  = (const float*)d_in[0];
    const int*   ei = (const int*)d_in[1];
    const float* W1 = (const float*)d_in[2];
    const float* b1 = (const float*)d_in[3];
    const float* W2 = (const float*)d_in[4];
    const float* b2 = (const float*)d_in[5];
    float* out = (float*)d_out;

    const int N = in_sizes[0] / FIN;     // 50000
    const int E = in_sizes[1] / 2;       // 800000
    const int* src = ei;
    const int* dst = ei + E;

    char* w = (char*)d_ws;
    auto alloc = [&](size_t bytes) {
        void* p = (void*)w;
        w += (bytes + 255) & ~(size_t)255;
        return p;
    };
    int*      deg    = (int*)alloc((size_t)N * 4);
    float*    dinv   = (float*)alloc((size_t)N * 4);
    int*      rowptr = (int*)alloc((size_t)(N + 1) * 4);
    int*      cursor = (int*)alloc((size_t)N * 4);
    int*      csr    = (int*)alloc((size_t)E * 4);
    int*      bsum   = (int*)alloc((size_t)256 * 4);
    _Float16* WT1    = (_Float16*)alloc((size_t)FIN * F1 * 2);
    _Float16* WT2    = (_Float16*)alloc((size_t)F1 * F2 * 2);
    _Float16* Hs1    = (_Float16*)alloc((size_t)N * F1 * 2);  // reused as Hs2
    float*    X2     = (float*)alloc((size_t)N * F1 * 4);

    const int nb = (N + 1023) / 1024;

    hipMemsetAsync(deg, 0, (size_t)N * 4, stream);
    count_deg<<<(E + 255) / 256, 256, 0, stream>>>(dst, deg, E);
    block_sum<<<nb, 256, 0, stream>>>(deg, bsum, N);
    scan_bsums<<<1, 64, 0, stream>>>(bsum, nb);
    scan_final<<<nb, 256, 0, stream>>>(deg, bsum, rowptr, cursor, dinv, N, E);
    fill_csr<<<(E + 255) / 256, 256, 0, stream>>>(src, dst, cursor, csr, E);
    cvt_wt<<<(FIN * F1 + 255) / 256, 256, 0, stream>>>(W1, WT1, FIN, F1);
    cvt_wt<<<(F1 * F2 + 255) / 256, 256, 0, stream>>>(W2, WT2, F1, F2);

    // layer 1: Hs1 = f16(dinv * (x @ W1)); X2 = relu(dinv*(Hs1[v]+sum)+b1)
    gemm_mfma<F1, FIN><<<(N + 63) / 64, 256, 0, stream>>>(x, WT1, dinv, Hs1, N);
    {
        int lpg = F1 / 4;                                 // 32 lanes/node
        int blocks = (int)(((size_t)N * lpg + 255) / 256);
        aggregate<F1, true><<<blocks, 256, 0, stream>>>(Hs1, rowptr, csr, dinv, b1, X2, N);
    }

    // layer 2: Hs2 = f16(dinv * (X2 @ W2)); out = dinv*(Hs2[v]+sum)+b2
    gemm_mfma<F2, F1><<<(N + 63) / 64, 256, 0, stream>>>(X2, WT2, dinv, Hs1, N);
    {
        int lpg = F2 / 4;                                 // 16 lanes/node
        int blocks = (int)(((size_t)N * lpg + 255) / 256);
        aggregate<F2, false><<<blocks, 256, 0, stream>>>(Hs1, rowptr, csr, dinv, b2, out, N);
    }
}

// Round 6
// 169.212 us; speedup vs baseline: 2.7212x; 1.2583x over previous
//
#include <hip/hip_runtime.h>

// ---------------- problem constants ----------------
#define FIN   256
#define F1    128
#define F2    64

typedef _Float16 f16x8 __attribute__((ext_vector_type(8)));
typedef _Float16 f16x4 __attribute__((ext_vector_type(4)));
typedef float    f32x4 __attribute__((ext_vector_type(4)));

// Buckets: 128 dst nodes per bucket (dst>>7). For N=50000 -> 391 buckets (<512).
#define BUCKET_SHIFT 7
#define BUCKET_W     128
#define MAXBUCK      512
#define CHUNK        2048   // edges per block in bucket passes

// ---------------- bucket histogram ----------------
__global__ __launch_bounds__(256) void bucket_hist(const int* __restrict__ dst,
                                                   int* __restrict__ bhist, int E) {
    __shared__ int h[MAXBUCK];
    for (int i = threadIdx.x; i < MAXBUCK; i += 256) h[i] = 0;
    __syncthreads();
    int base = blockIdx.x * CHUNK;
#pragma unroll
    for (int i = 0; i < CHUNK / 256; ++i) {
        int e = base + i * 256 + threadIdx.x;
        if (e < E) atomicAdd(&h[dst[e] >> BUCKET_SHIFT], 1);
    }
    __syncthreads();
    for (int i = threadIdx.x; i < MAXBUCK; i += 256)
        if (h[i]) atomicAdd(&bhist[i], h[i]);
}

// ---------------- scan buckets (1 block, 512 threads) ----------------
__global__ __launch_bounds__(512) void scan_bucket(const int* __restrict__ bhist,
                                                   int* __restrict__ bbase,
                                                   int* __restrict__ bcur_pad,
                                                   int nbuck, int E) {
    __shared__ int buf[2][512];
    int t = threadIdx.x;
    int v = (t < nbuck) ? bhist[t] : 0;
    buf[0][t] = v;
    __syncthreads();
    int cur = 0;
    for (int off = 1; off < 512; off <<= 1) {
        int x = buf[cur][t];
        if (t >= off) x += buf[cur][t - off];
        buf[cur ^ 1][t] = x;
        cur ^= 1;
        __syncthreads();
    }
    int excl = (t == 0) ? 0 : buf[cur][t - 1];
    if (t < nbuck) {
        bbase[t] = excl;
        bcur_pad[t * 16] = excl;      // 64B-padded cursor (atomic target)
    }
    if (t == 0) bbase[nbuck] = E;
}

// ---------------- partition edges into bucket-segmented ebuf ----------------
__global__ __launch_bounds__(256) void bucket_fill(const int* __restrict__ src,
                                                   const int* __restrict__ dst,
                                                   int* __restrict__ bcur_pad,
                                                   uint2* __restrict__ ebuf, int E) {
    __shared__ int h[MAXBUCK];
    __shared__ int base[MAXBUCK];
    for (int i = threadIdx.x; i < MAXBUCK; i += 256) h[i] = 0;
    __syncthreads();
    int cbase = blockIdx.x * CHUNK;
#pragma unroll
    for (int i = 0; i < CHUNK / 256; ++i) {
        int e = cbase + i * 256 + threadIdx.x;
        if (e < E) atomicAdd(&h[dst[e] >> BUCKET_SHIFT], 1);
    }
    __syncthreads();
    for (int i = threadIdx.x; i < MAXBUCK; i += 256) {
        int c = h[i];
        base[i] = c ? atomicAdd(&bcur_pad[i * 16], c) : 0;
        h[i] = 0;
    }
    __syncthreads();
#pragma unroll
    for (int i = 0; i < CHUNK / 256; ++i) {
        int e = cbase + i * 256 + threadIdx.x;
        if (e < E) {
            int d = dst[e], b = d >> BUCKET_SHIFT;
            int r = atomicAdd(&h[b], 1);
            ebuf[base[b] + r] = make_uint2((unsigned)src[e], (unsigned)d);
        }
    }
}

// ---------------- per-bucket degree count (LDS only) ----------------
__global__ __launch_bounds__(256) void deg_bucket(const uint2* __restrict__ ebuf,
                                                  const int* __restrict__ bbase,
                                                  int* __restrict__ deg, int n) {
    __shared__ int cnt[BUCKET_W];
    int k = blockIdx.x;
    if (threadIdx.x < BUCKET_W) cnt[threadIdx.x] = 0;
    __syncthreads();
    int beg = bbase[k], end = bbase[k + 1];
    for (int e = beg + threadIdx.x; e < end; e += 256)
        atomicAdd(&cnt[ebuf[e].y & (BUCKET_W - 1)], 1);
    __syncthreads();
    if (threadIdx.x < BUCKET_W) {
        int node = (k << BUCKET_SHIFT) + threadIdx.x;
        if (node < n) deg[node] = cnt[threadIdx.x];
    }
}

// ---------------- hierarchical scan over deg -> rowptr, dinv ----------------
__global__ __launch_bounds__(256) void block_sum(const int* __restrict__ deg,
                                                 int* __restrict__ bsum, int n) {
    int t = threadIdx.x;
    int base = blockIdx.x * 1024 + t * 4;
    int s = 0;
    if (base + 3 < n) {
        int4 v = *(const int4*)&deg[base];
        s = v.x + v.y + v.z + v.w;
    } else {
        for (int i = 0; i < 4; ++i)
            if (base + i < n) s += deg[base + i];
    }
#pragma unroll
    for (int off = 32; off > 0; off >>= 1) s += __shfl_down(s, off, 64);
    __shared__ int ws[4];
    if ((t & 63) == 0) ws[t >> 6] = s;
    __syncthreads();
    if (t == 0) bsum[blockIdx.x] = ws[0] + ws[1] + ws[2] + ws[3];
}

__global__ void scan_bsums(int* __restrict__ bsum, int nb) {
    if (threadIdx.x == 0) {
        int run = 0;
        for (int i = 0; i < nb; ++i) {
            int v = bsum[i];
            bsum[i] = run;
            run += v;
        }
    }
}

__global__ __launch_bounds__(256) void scan_final(const int* __restrict__ deg,
                                                  const int* __restrict__ bsum,
                                                  int* __restrict__ rowptr,
                                                  float* __restrict__ dinv,
                                                  int n, int E) {
    __shared__ int buf[2][256];
    int t = threadIdx.x;
    int base = blockIdx.x * 1024 + t * 4;
    int d[4] = {0, 0, 0, 0};
    if (base + 3 < n) {
        int4 v = *(const int4*)&deg[base];
        d[0] = v.x; d[1] = v.y; d[2] = v.z; d[3] = v.w;
    } else {
        for (int i = 0; i < 4; ++i)
            if (base + i < n) d[i] = deg[base + i];
    }
    int tsum = d[0] + d[1] + d[2] + d[3];
    buf[0][t] = tsum;
    __syncthreads();
    int cur = 0;
    for (int off = 1; off < 256; off <<= 1) {
        int v = buf[cur][t];
        if (t >= off) v += buf[cur][t - off];
        buf[cur ^ 1][t] = v;
        cur ^= 1;
        __syncthreads();
    }
    int run = bsum[blockIdx.x] + ((t == 0) ? 0 : buf[cur][t - 1]);
#pragma unroll
    for (int i = 0; i < 4; ++i) {
        int idx = base + i;
        if (idx < n) {
            rowptr[idx] = run;
            dinv[idx]   = rsqrtf((float)(d[i] + 1));  // +1 self loop
            run += d[i];
        }
    }
    if (blockIdx.x == 0 && t == 0) rowptr[n] = E;
}

// ---------------- per-bucket CSR fill (one block owns one csr window) -------
__global__ __launch_bounds__(256) void csr_fill_bucket(const uint2* __restrict__ ebuf,
                                                       const int* __restrict__ bbase,
                                                       const int* __restrict__ rowptr,
                                                       int* __restrict__ csr, int n) {
    __shared__ int lcur[BUCKET_W];
    int k = blockIdx.x;
    if (threadIdx.x < BUCKET_W) {
        int node = (k << BUCKET_SHIFT) + threadIdx.x;
        lcur[threadIdx.x] = (node < n) ? rowptr[node] : 0;
    }
    __syncthreads();
    int beg = bbase[k], end = bbase[k + 1];
    for (int e = beg + threadIdx.x; e < end; e += 256) {
        uint2 ed = ebuf[e];
        int pos = atomicAdd(&lcur[ed.y & (BUCKET_W - 1)], 1);
        csr[pos] = (int)ed.x;
    }
}

// ---------------- W -> W^T f16 conversion ----------------
__global__ void cvt_wt(const float* __restrict__ W, _Float16* __restrict__ WT,
                       int K, int Nn) {
    int idx = blockIdx.x * blockDim.x + threadIdx.x;
    if (idx < K * Nn) {
        int k = idx / Nn, n = idx % Nn;
        WT[(size_t)n * K + k] = (_Float16)W[idx];
    }
}

// ---------------- f16 MFMA GEMM, f16 output, dinv-scaled epilogue ----------------
template <int BN, int K>
__global__ __launch_bounds__(256) void gemm_mfma(const float* __restrict__ A,
                                                 const _Float16* __restrict__ WT,
                                                 const float* __restrict__ dinv,
                                                 _Float16* __restrict__ Ch, int M) {
    constexpr int NB = BN / 16;
    __shared__ _Float16 As[64][72];

    int tid  = threadIdx.x;
    int wave = tid >> 6, lane = tid & 63;
    int col  = lane & 15, kg = lane >> 4;
    int row0 = blockIdx.x * 64;

    f32x4 acc[NB];
#pragma unroll
    for (int j = 0; j < NB; ++j) acc[j] = (f32x4){0.f, 0.f, 0.f, 0.f};

    for (int k0 = 0; k0 < K; k0 += 64) {
#pragma unroll
        for (int l = 0; l < 4; ++l) {
            int f  = l * 256 + tid;
            int r  = f >> 4;
            int c4 = f & 15;
            int gr = row0 + r;
            float4 v = make_float4(0.f, 0.f, 0.f, 0.f);
            if (gr < M) v = *(const float4*)&A[(size_t)gr * K + k0 + c4 * 4];
            f16x4 h;
            h[0] = (_Float16)v.x; h[1] = (_Float16)v.y;
            h[2] = (_Float16)v.z; h[3] = (_Float16)v.w;
            *(f16x4*)&As[r][c4 * 4] = h;
        }
        __syncthreads();
#pragma unroll
        for (int kk = 0; kk < 2; ++kk) {
            f16x8 a = *(const f16x8*)&As[wave * 16 + col][kk * 32 + kg * 8];
#pragma unroll
            for (int j = 0; j < NB; ++j) {
                f16x8 b = *(const f16x8*)&WT[(size_t)(j * 16 + col) * K + k0 + kk * 32 + kg * 8];
                acc[j] = __builtin_amdgcn_mfma_f32_16x16x32_f16(a, b, acc[j], 0, 0, 0);
            }
        }
        __syncthreads();
    }
    int rbase = row0 + wave * 16 + kg * 4;
#pragma unroll
    for (int r = 0; r < 4; ++r) {
        int m = rbase + r;
        if (m < M) {
            float dv = dinv[m];
#pragma unroll
            for (int j = 0; j < NB; ++j)
                Ch[(size_t)m * BN + j * 16 + col] = (_Float16)(dv * acc[j][r]);
        }
    }
}

// ---------------- gather aggregation: f16 rows, f32 accumulate ----------------
template <int F, bool RELU>
__global__ __launch_bounds__(256) void aggregate(const _Float16* __restrict__ Hs,
                                                 const int* __restrict__ rowptr,
                                                 const int* __restrict__ csr,
                                                 const float* __restrict__ dinv,
                                                 const float* __restrict__ bias,
                                                 float* __restrict__ out, int n) {
    constexpr int LPG = F / 4;                  // 32 (F=128) or 16 (F=64)
    int gid = (blockIdx.x * blockDim.x + threadIdx.x) / LPG;
    int sub = threadIdx.x & (LPG - 1);
    if (gid >= n) return;
    const int col = sub * 4;

    f16x4 h = *(const f16x4*)&Hs[(size_t)gid * F + col];
    float a0 = (float)h[0], a1 = (float)h[1], a2 = (float)h[2], a3 = (float)h[3];

    int beg = rowptr[gid], end = rowptr[gid + 1];
    int e = beg;

    for (; e + 8 <= end; e += 8) {
        int s0 = csr[e + 0], s1 = csr[e + 1], s2 = csr[e + 2], s3 = csr[e + 3];
        int s4 = csr[e + 4], s5 = csr[e + 5], s6 = csr[e + 6], s7 = csr[e + 7];
        f16x4 v0 = *(const f16x4*)&Hs[(size_t)s0 * F + col];
        f16x4 v1 = *(const f16x4*)&Hs[(size_t)s1 * F + col];
        f16x4 v2 = *(const f16x4*)&Hs[(size_t)s2 * F + col];
        f16x4 v3 = *(const f16x4*)&Hs[(size_t)s3 * F + col];
        f16x4 v4 = *(const f16x4*)&Hs[(size_t)s4 * F + col];
        f16x4 v5 = *(const f16x4*)&Hs[(size_t)s5 * F + col];
        f16x4 v6 = *(const f16x4*)&Hs[(size_t)s6 * F + col];
        f16x4 v7 = *(const f16x4*)&Hs[(size_t)s7 * F + col];
        a0 += (((float)v0[0] + (float)v1[0]) + ((float)v2[0] + (float)v3[0]))
            + (((float)v4[0] + (float)v5[0]) + ((float)v6[0] + (float)v7[0]));
        a1 += (((float)v0[1] + (float)v1[1]) + ((float)v2[1] + (float)v3[1]))
            + (((float)v4[1] + (float)v5[1]) + ((float)v6[1] + (float)v7[1]));
        a2 += (((float)v0[2] + (float)v1[2]) + ((float)v2[2] + (float)v3[2]))
            + (((float)v4[2] + (float)v5[2]) + ((float)v6[2] + (float)v7[2]));
        a3 += (((float)v0[3] + (float)v1[3]) + ((float)v2[3] + (float)v3[3]))
            + (((float)v4[3] + (float)v5[3]) + ((float)v6[3] + (float)v7[3]));
    }
    for (; e + 4 <= end; e += 4) {
        int s0 = csr[e + 0], s1 = csr[e + 1], s2 = csr[e + 2], s3 = csr[e + 3];
        f16x4 v0 = *(const f16x4*)&Hs[(size_t)s0 * F + col];
        f16x4 v1 = *(const f16x4*)&Hs[(size_t)s1 * F + col];
        f16x4 v2 = *(const f16x4*)&Hs[(size_t)s2 * F + col];
        f16x4 v3 = *(const f16x4*)&Hs[(size_t)s3 * F + col];
        a0 += ((float)v0[0] + (float)v1[0]) + ((float)v2[0] + (float)v3[0]);
        a1 += ((float)v0[1] + (float)v1[1]) + ((float)v2[1] + (float)v3[1]);
        a2 += ((float)v0[2] + (float)v1[2]) + ((float)v2[2] + (float)v3[2]);
        a3 += ((float)v0[3] + (float)v1[3]) + ((float)v2[3] + (float)v3[3]);
    }
    for (; e < end; ++e) {
        int s = csr[e];
        f16x4 v = *(const f16x4*)&Hs[(size_t)s * F + col];
        a0 += (float)v[0]; a1 += (float)v[1]; a2 += (float)v[2]; a3 += (float)v[3];
    }

    float dv = dinv[gid];
    float4 bb = *(const float4*)&bias[col];
    float4 o;
    o.x = dv * a0 + bb.x;
    o.y = dv * a1 + bb.y;
    o.z = dv * a2 + bb.z;
    o.w = dv * a3 + bb.w;
    if (RELU) {
        o.x = fmaxf(o.x, 0.f); o.y = fmaxf(o.y, 0.f);
        o.z = fmaxf(o.z, 0.f); o.w = fmaxf(o.w, 0.f);
    }
    *(float4*)&out[(size_t)gid * F + col] = o;
}

// ---------------- launch ----------------
extern "C" void kernel_launch(void* const* d_in, const int* in_sizes, int n_in,
                              void* d_out, int out_size, void* d_ws, size_t ws_size,
                              hipStream_t stream) {
    const float* x  = (const float*)d_in[0];
    const int*   ei = (const int*)d_in[1];
    const float* W1 = (const float*)d_in[2];
    const float* b1 = (const float*)d_in[3];
    const float* W2 = (const float*)d_in[4];
    const float* b2 = (const float*)d_in[5];
    float* out = (float*)d_out;

    const int N = in_sizes[0] / FIN;     // 50000
    const int E = in_sizes[1] / 2;       // 800000
    const int* src = ei;
    const int* dst = ei + E;

    char* w = (char*)d_ws;
    auto alloc = [&](size_t bytes) {
        void* p = (void*)w;
        w += (bytes + 255) & ~(size_t)255;
        return p;
    };
    int*      deg      = (int*)alloc((size_t)N * 4);
    float*    dinv     = (float*)alloc((size_t)N * 4);
    int*      rowptr   = (int*)alloc((size_t)(N + 1) * 4);
    int*      csr      = (int*)alloc((size_t)E * 4);
    int*      bsum     = (int*)alloc((size_t)256 * 4);
    int*      bhist    = (int*)alloc((size_t)MAXBUCK * 4);
    int*      bbase    = (int*)alloc((size_t)(MAXBUCK + 1) * 4);
    int*      bcur_pad = (int*)alloc((size_t)MAXBUCK * 16 * 4);
    uint2*    ebuf     = (uint2*)alloc((size_t)E * 8);
    _Float16* WT1      = (_Float16*)alloc((size_t)FIN * F1 * 2);
    _Float16* WT2      = (_Float16*)alloc((size_t)F1 * F2 * 2);
    _Float16* Hs1      = (_Float16*)alloc((size_t)N * F1 * 2);  // reused as Hs2
    float*    X2       = (float*)alloc((size_t)N * F1 * 4);

    const int nb     = (N + 1023) / 1024;
    const int nbuck  = (N + BUCKET_W - 1) >> BUCKET_SHIFT;   // 391
    const int nchunk = (E + CHUNK - 1) / CHUNK;

    // ---- CSR build (bucketized) ----
    hipMemsetAsync(bhist, 0, (size_t)MAXBUCK * 4, stream);
    bucket_hist<<<nchunk, 256, 0, stream>>>(dst, bhist, E);
    scan_bucket<<<1, 512, 0, stream>>>(bhist, bbase, bcur_pad, nbuck, E);
    bucket_fill<<<nchunk, 256, 0, stream>>>(src, dst, bcur_pad, ebuf, E);
    deg_bucket<<<nbuck, 256, 0, stream>>>(ebuf, bbase, deg, N);
    block_sum<<<nb, 256, 0, stream>>>(deg, bsum, N);
    scan_bsums<<<1, 64, 0, stream>>>(bsum, nb);
    scan_final<<<nb, 256, 0, stream>>>(deg, bsum, rowptr, dinv, N, E);
    csr_fill_bucket<<<nbuck, 256, 0, stream>>>(ebuf, bbase, rowptr, csr, N);

    // ---- weights ----
    cvt_wt<<<(FIN * F1 + 255) / 256, 256, 0, stream>>>(W1, WT1, FIN, F1);
    cvt_wt<<<(F1 * F2 + 255) / 256, 256, 0, stream>>>(W2, WT2, F1, F2);

    // layer 1: Hs1 = f16(dinv * (x @ W1)); X2 = relu(dinv*(Hs1[v]+sum)+b1)
    gemm_mfma<F1, FIN><<<(N + 63) / 64, 256, 0, stream>>>(x, WT1, dinv, Hs1, N);
    {
        int lpg = F1 / 4;
        int blocks = (int)(((size_t)N * lpg + 255) / 256);
        aggregate<F1, true><<<blocks, 256, 0, stream>>>(Hs1, rowptr, csr, dinv, b1, X2, N);
    }

    // layer 2: Hs2 = f16(dinv * (X2 @ W2)); out = dinv*(Hs2[v]+sum)+b2
    gemm_mfma<F2, F1><<<(N + 63) / 64, 256, 0, stream>>>(X2, WT2, dinv, Hs1, N);
    {
        int lpg = F2 / 4;
        int blocks = (int)(((size_t)N * lpg + 255) / 256);
        aggregate<F2, false><<<blocks, 256, 0, stream>>>(Hs1, rowptr, csr, dinv, b2, out, N);
    }
}